// Round 12
// baseline (257.242 us; speedup 1.0000x reference)
//
#include <hip/hip_runtime.h>
#include <math.h>

#define H 128
#define TOPK 5
#define INV_TEMP 5.0f
#define ZLD 2064      // z2t row stride in floats (non-pow2, 16B-aligned)
#define ZN 8          // zero-nodes per group
#define JQ 512        // j-columns per task (quarter of NRES)
#define ZSB 1024      // zero_sims blocks at the front of the fused kernel

typedef __attribute__((ext_vector_type(8))) short short8;
typedef __attribute__((ext_vector_type(4))) float f32x4;

__device__ __forceinline__ unsigned bf16_rne(float x) {
  unsigned u = __float_as_uint(x);
  return (u + 0x7FFFu + ((u >> 16) & 1u)) >> 16;
}
__device__ __forceinline__ unsigned pk_bf16(float lo, float hi) {
  return bf16_rne(lo) | (bf16_rne(hi) << 16);
}

// ---------------- degree count + rank (atomic) ∥ W->bf16 ∥ z2t norm-transpose ----------------
__global__ __launch_bounds__(256) void deg_fill_kernel(
    const int* __restrict__ src, const int* __restrict__ dst,
    int* __restrict__ in_deg, int* __restrict__ out_flag,
    int* __restrict__ pos, int E,
    const float* __restrict__ W1, const float* __restrict__ W2,
    unsigned short* __restrict__ W1b, unsigned short* __restrict__ W2b,
    const float* __restrict__ res, float* __restrict__ z2t, int NRES_)
{
  int EB = (E + 255) >> 8;
  int b = blockIdx.x;
  if (b < EB) {
    int e = b * 256 + threadIdx.x;
    if (e < E) {
      pos[e] = atomicAdd(&in_deg[dst[e]], 1);
      out_flag[src[e]] = 1;
    }
  } else if (b < EB + 32) {
    int b2 = b - EB;               // 0..31
    const float* Wsrc = (b2 < 16) ? W1 : W2;
    unsigned short* Wdst = (b2 < 16) ? W1b : W2b;
    int base = (b2 & 15) * 1024 + threadIdx.x * 4;
    float4 v = *(const float4*)&Wsrc[base];
    uint2 p = make_uint2(pk_bf16(v.x, v.y), pk_bf16(v.z, v.w));
    *(uint2*)&Wdst[base] = p;
  } else {
    int r = (b - EB - 32) * 4 + (threadIdx.x >> 6);
    int lane = threadIdx.x & 63;
    if (r < NRES_) {
      float x0 = res[(size_t)r * H + lane];
      float x1 = res[(size_t)r * H + lane + 64];
      float ss = x0 * x0 + x1 * x1;
      #pragma unroll
      for (int off = 32; off > 0; off >>= 1) ss += __shfl_xor(ss, off, 64);
      float iv = 1.0f / fmaxf(sqrtf(ss), 1e-12f);
      z2t[(size_t)lane * ZLD + r] = x0 * iv;
      z2t[(size_t)(lane + 64) * ZLD + r] = x1 * iv;
    }
  }
}

// ---------------- atomic-free bucket scatter ----------------
__global__ __launch_bounds__(256) void scatter_kernel(
    const int* __restrict__ dst, const int* __restrict__ rel, const int* __restrict__ inv,
    const int* __restrict__ offs, const int* __restrict__ pos,
    int* __restrict__ bucket, int E)
{
  int e = blockIdx.x * 256 + threadIdx.x;
  if (e < E)
    bucket[offs[dst[e]] + pos[e]] = rel[e] | (inv[e] << 16);
}

// ---------------- fused: scan (block 0) + zerolist + z1-normalize into feat ----------------
// z1norm blocks need no zlist: they re-test (in_deg|out_flag)==0 per node
// range, compact to LDS, then wave-per-row normalize ent -> feat.
__global__ __launch_bounds__(1024) void prep_kernel(
    const int* __restrict__ in_deg, const int* __restrict__ out_flag,
    int* __restrict__ offs,
    int* __restrict__ zlist, int* __restrict__ zcount, int N,
    const float* __restrict__ ent, float* __restrict__ feat)
{
  __shared__ int sums[1024];
  __shared__ int lst[2048];
  __shared__ int lcnt;
  int b = blockIdx.x;
  int nbz = (N + 1023) >> 10;
  if (b == 0) {
    int tid = threadIdx.x;
    int per = (((N + 1023) >> 10) + 3) & ~3;
    int start = tid * per;
    int end = min(start + per, N);
    int s = 0;
    int i = start;
    for (; i + 4 <= end; i += 4) {
      int4 v = *(const int4*)&in_deg[i];
      s += v.x + v.y + v.z + v.w;
    }
    for (; i < end; ++i) s += in_deg[i];
    sums[tid] = s;
    __syncthreads();
    for (int off = 1; off < 1024; off <<= 1) {
      int v = (tid >= off) ? sums[tid - off] : 0;
      __syncthreads();
      sums[tid] += v;
      __syncthreads();
    }
    int run = (tid == 0) ? 0 : sums[tid - 1];
    i = start;
    for (; i + 4 <= end; i += 4) {
      int4 v = *(const int4*)&in_deg[i];
      int4 o;
      o.x = run; run += v.x;
      o.y = run; run += v.y;
      o.z = run; run += v.z;
      o.w = run; run += v.w;
      *(int4*)&offs[i] = o;
    }
    for (; i < end; ++i) { offs[i] = run; run += in_deg[i]; }
    if (tid == 1023) offs[N] = sums[1023];
  } else if (b <= nbz) {
    int n = (b - 1) * 1024 + threadIdx.x;
    if (n < N && (in_deg[n] | out_flag[n]) == 0) {
      int p = atomicAdd(zcount, 1);
      zlist[p] = n;
    }
  } else {
    // z1 normalize: 2048-node range per block
    int base0 = (b - nbz - 1) * 2048;
    if (threadIdx.x == 0) lcnt = 0;
    __syncthreads();
    #pragma unroll
    for (int ii = 0; ii < 2; ++ii) {
      int n = base0 + ii * 1024 + threadIdx.x;
      if (n < N && (in_deg[n] | out_flag[n]) == 0) {
        int p = atomicAdd(&lcnt, 1);
        lst[p] = n;
      }
    }
    __syncthreads();
    int w = threadIdx.x >> 6, lane = threadIdx.x & 63;
    int L = lcnt;
    for (int i = w; i < L; i += 16) {
      int n = lst[i];
      float x0 = ent[(size_t)n * H + lane];
      float x1 = ent[(size_t)n * H + lane + 64];
      float ss = x0 * x0 + x1 * x1;
      #pragma unroll
      for (int off = 32; off > 0; off >>= 1) ss += __shfl_xor(ss, off, 64);
      float iv = 1.0f / fmaxf(sqrtf(ss), 1e-12f);
      feat[(size_t)n * H + lane] = x0 * iv;
      feat[(size_t)n * H + lane + 64] = x1 * iv;
    }
  }
}

// ---------------- FUSED: zero_sims (blocks [0,ZSB)) ∥ gather (blocks [ZSB,ZSB+GB)) ----------------
// zero_sims: VALU-bound; gather: memory-latency-bound. Co-resident blocks
// overlap the two pipes. z1 rows pre-normalized into feat by prep_kernel.
__global__ __launch_bounds__(256) void gsim_kernel(
    const int* __restrict__ offs, const int* __restrict__ bucket,
    const int* __restrict__ out_flag,
    const float* __restrict__ rhead, const float* __restrict__ rtail,
    float* __restrict__ feat, int N,
    const int* __restrict__ zlist, const int* __restrict__ zcount,
    const float* __restrict__ z2t, float2* __restrict__ partials, int NRES_)
{
  __shared__ __align__(16) float sims[ZN * JQ];   // 16 KB (zero_sims blocks only)
  int t = threadIdx.x;
  int lane = t & 63;
  if ((int)blockIdx.x < ZSB) {
    // ================= zero_sims =================
    int w = t >> 6;
    int Z = *zcount;
    if (Z <= 0) return;
    int ntasks = ((Z + ZN - 1) / ZN) * 4;
    for (int task = blockIdx.x; task < ntasks; task += ZSB) {
      int g = task >> 2, q = task & 3;
      int zi0 = g * ZN;
      int nv = min(ZN, Z - zi0);
      const float* zp[ZN];
      #pragma unroll
      for (int n = 0; n < ZN; ++n) {
        int zi = zi0 + n; if (zi > Z - 1) zi = Z - 1;
        int node = __builtin_amdgcn_readfirstlane(zlist[zi]);
        zp[n] = feat + (size_t)node * H;
      }
      int jl0 = 2 * t;
      const float* zc = z2t + q * JQ + jl0;
      float acc[ZN][2];
      #pragma unroll
      for (int n = 0; n < ZN; ++n) { acc[n][0] = 0.f; acc[n][1] = 0.f; }
      #pragma unroll 2
      for (int k0 = 0; k0 < H; k0 += 4) {
        float2 c0 = *(const float2*)(zc + (size_t)(k0 + 0) * ZLD);
        float2 c1 = *(const float2*)(zc + (size_t)(k0 + 1) * ZLD);
        float2 c2 = *(const float2*)(zc + (size_t)(k0 + 2) * ZLD);
        float2 c3 = *(const float2*)(zc + (size_t)(k0 + 3) * ZLD);
        #pragma unroll
        for (int n = 0; n < ZN; ++n) {
          float4 z = *(const float4*)(zp[n] + k0);   // SGPR base -> s_load
          acc[n][0] = fmaf(z.x, c0.x, acc[n][0]);
          acc[n][1] = fmaf(z.x, c0.y, acc[n][1]);
          acc[n][0] = fmaf(z.y, c1.x, acc[n][0]);
          acc[n][1] = fmaf(z.y, c1.y, acc[n][1]);
          acc[n][0] = fmaf(z.z, c2.x, acc[n][0]);
          acc[n][1] = fmaf(z.z, c2.y, acc[n][1]);
          acc[n][0] = fmaf(z.w, c3.x, acc[n][0]);
          acc[n][1] = fmaf(z.w, c3.y, acc[n][1]);
        }
      }
      int j0g = q * JQ + jl0;
      #pragma unroll
      for (int n = 0; n < ZN; ++n) {
        float v0 = (j0g + 0 < NRES_) ? acc[n][0] : -1e30f;
        float v1 = (j0g + 1 < NRES_) ? acc[n][1] : -1e30f;
        *(float2*)&sims[n * JQ + jl0] = make_float2(v0, v1);
      }
      __syncthreads();
      #pragma unroll
      for (int c = 0; c < 2; ++c) {
        int nl = w * 2 + c;
        if (nl < nv) {
          float tv[TOPK]; int ti[TOPK];
          #pragma unroll
          for (int k = 0; k < TOPK; ++k) { tv[k] = -1e30f; ti[k] = 0x7fffffff; }
          #pragma unroll
          for (int i = 0; i < JQ / 64; ++i) {
            int jl = i * 64 + lane;
            float s = sims[nl * JQ + jl];
            int j = q * JQ + jl;
            if (s > tv[TOPK - 1] || (s == tv[TOPK - 1] && j < ti[TOPK - 1])) {
              tv[TOPK - 1] = s; ti[TOPK - 1] = j;
              #pragma unroll
              for (int k = TOPK - 1; k > 0; --k) {
                if (tv[k] > tv[k - 1] || (tv[k] == tv[k - 1] && ti[k] < ti[k - 1])) {
                  float a = tv[k]; tv[k] = tv[k - 1]; tv[k - 1] = a;
                  int bI = ti[k]; ti[k] = ti[k - 1]; ti[k - 1] = bI;
                }
              }
            }
          }
          #pragma unroll
          for (int r = 0; r < TOPK; ++r) {
            float bv = tv[0]; int bi = ti[0];
            #pragma unroll
            for (int k = 1; k < TOPK; ++k)
              if (tv[k] > bv || (tv[k] == bv && ti[k] < bi)) { bv = tv[k]; bi = ti[k]; }
            #pragma unroll
            for (int off = 32; off > 0; off >>= 1) {
              float ov = __shfl_xor(bv, off, 64);
              int oi = __shfl_xor(bi, off, 64);
              if (ov > bv || (ov == bv && oi < bi)) { bv = ov; bi = oi; }
            }
            if (lane == r)
              partials[((size_t)task * ZN + nl) * TOPK + r] =
                  make_float2(bv, __int_as_float(bi));
            #pragma unroll
            for (int k = 0; k < TOPK; ++k)
              if (ti[k] == bi) tv[k] = -1e30f;
          }
        }
      }
      __syncthreads();
    }
    return;
  }
  // ================= gather =================
  int wid = ((blockIdx.x - ZSB) * 256 + t) >> 6;
  if (wid >= N) return;
  int b = offs[wid], e2 = offs[wid + 1];
  int deg = e2 - b;
  if (deg == 0 && out_flag[wid] == 0) return;   // z1 row lives here
  float a0 = 0.f, a1 = 0.f;
  int pay = (b < e2) ? bucket[b] : 0;
  for (int p = b; p < e2; ++p) {
    int pn = (p + 1 < e2) ? bucket[p + 1] : 0;
    int r = pay & 0xFFFF;
    const float* row = ((pay >> 16) ? rhead : rtail) + (size_t)r * H;
    a0 += row[lane];
    a1 += row[lane + 64];
    pay = pn;
  }
  float sc = 1.0f / (float)(deg > 0 ? deg : 1);
  feat[(size_t)wid * H + lane] = a0 * sc;
  feat[(size_t)wid * H + lane + 64] = a1 * sc;
}

// ---------------- merge 4 quarter top-5s -> softmax -> weighted sum ----------------
__global__ __launch_bounds__(256) void zmerge_kernel(
    const int* __restrict__ zlist, const int* __restrict__ zcount,
    const float2* __restrict__ partials, const float* __restrict__ res_raw,
    float* __restrict__ feat, int NRES_)
{
  int gid = blockIdx.x * 256 + threadIdx.x;
  int wid = gid >> 6;
  int lane = gid & 63;
  int nw = (gridDim.x * 256) >> 6;
  int Z = *zcount;
  for (int nz = wid; nz < Z; nz += nw) {
    int g = nz >> 3, w = nz & 7;
    float v = -1e30f; int idx = 0x7fffffff;
    if (lane < 4 * TOPK) {
      int q = lane / TOPK, k = lane - q * TOPK;
      float2 p = partials[((size_t)(g * 4 + q) * ZN + w) * TOPK + k];
      v = p.x; idx = __float_as_int(p.y);
    }
    bool used = false;
    float m = 0.f, wsum = 0.f, a0 = 0.f, a1 = 0.f;
    #pragma unroll
    for (int r = 0; r < TOPK; ++r) {
      float bv = used ? -1e31f : v;
      int bi = used ? 0x7fffffff : idx;
      #pragma unroll
      for (int off = 32; off > 0; off >>= 1) {
        float ov = __shfl_xor(bv, off, 64);
        int oi = __shfl_xor(bi, off, 64);
        if (ov > bv || (ov == bv && oi < bi)) { bv = ov; bi = oi; }
      }
      if (r == 0) m = bv;
      bool ok = (unsigned)bi < (unsigned)NRES_;
      float wk = ok ? expf((bv - m) * INV_TEMP) : 0.f;
      wsum += wk;
      const float* rr = res_raw + (size_t)(ok ? bi : 0) * H;
      a0 += wk * rr[lane];
      a1 += wk * rr[lane + 64];
      if (idx == bi) used = true;
    }
    float inv_ws = 1.0f / wsum;
    int n = zlist[nz];
    feat[(size_t)n * H + lane] = a0 * inv_ws;
    feat[(size_t)n * H + lane + 64] = a1 * inv_ws;
  }
}

// ---------------- fused 2-layer MLP via bf16 MFMA ----------------
__global__ __launch_bounds__(256) void mlp_kernel(
    const float* __restrict__ feat,
    const unsigned short* __restrict__ W1b, const float* __restrict__ b1,
    const unsigned short* __restrict__ W2b, const float* __restrict__ b2,
    float* __restrict__ out, int N)
{
  __shared__ float lds[64 * 128];   // 32 KB
  char* ldsb = (char*)lds;
  int t = threadIdx.x;
  int lane = t & 63;
  int w = t >> 6;
  int row0 = blockIdx.x * 64;

  for (int idx = t; idx < 64 * 32; idx += 256) {
    int r = idx >> 5, q = idx & 31;
    float4 v = make_float4(0.f, 0.f, 0.f, 0.f);
    if (row0 + r < N) v = *(const float4*)&feat[(size_t)(row0 + r) * H + q * 4];
    int byte = (r * 512 + q * 16) ^ ((r & 7) << 4);
    *(float4*)(ldsb + byte) = v;
  }
  __syncthreads();

  int m0 = w * 16;
  int col = lane & 15;
  int kg = lane >> 4;
  int am = m0 + col;
  int aswz = (am & 7) << 4;

  float bias1[8], bias2[8];
  #pragma unroll
  for (int nt = 0; nt < 8; ++nt) {
    bias1[nt] = b1[nt * 16 + col];
    bias2[nt] = b2[nt * 16 + col];
  }

  short8 afr[4];
  f32x4 acc[8];

  // ---- layer 1 ----
  #pragma unroll
  for (int ks = 0; ks < 4; ++ks) {
    int base = am * 512 + ks * 128 + kg * 32;
    float4 lo = *(float4*)(ldsb + (base ^ aswz));
    float4 hi = *(float4*)(ldsb + ((base + 16) ^ aswz));
    union { unsigned u[4]; short8 s; } cv;
    cv.u[0] = pk_bf16(lo.x, lo.y); cv.u[1] = pk_bf16(lo.z, lo.w);
    cv.u[2] = pk_bf16(hi.x, hi.y); cv.u[3] = pk_bf16(hi.z, hi.w);
    afr[ks] = cv.s;
  }
  #pragma unroll
  for (int nt = 0; nt < 8; ++nt) {
    f32x4 a; a[0] = a[1] = a[2] = a[3] = bias1[nt];
    acc[nt] = a;
    const unsigned short* wrow = W1b + (size_t)(nt * 16 + col) * H + kg * 8;
    #pragma unroll
    for (int ks = 0; ks < 4; ++ks) {
      union { int4 i; short8 s; } bv;
      bv.i = *(const int4*)(wrow + ks * 32);
      acc[nt] = __builtin_amdgcn_mfma_f32_16x16x32_bf16(afr[ks], bv.s, acc[nt], 0, 0, 0);
    }
  }
  __syncthreads();
  #pragma unroll
  for (int nt = 0; nt < 8; ++nt) {
    int n = nt * 16 + col;
    #pragma unroll
    for (int r = 0; r < 4; ++r) {
      int m = m0 + kg * 4 + r;
      int byte = (m * 512 + n * 4) ^ ((m & 7) << 4);
      *(float*)(ldsb + byte) = fmaxf(acc[nt][r], 0.f);
    }
  }
  __syncthreads();

  // ---- layer 2 ----
  #pragma unroll
  for (int ks = 0; ks < 4; ++ks) {
    int base = am * 512 + ks * 128 + kg * 32;
    float4 lo = *(float4*)(ldsb + (base ^ aswz));
    float4 hi = *(float4*)(ldsb + ((base + 16) ^ aswz));
    union { unsigned u[4]; short8 s; } cv;
    cv.u[0] = pk_bf16(lo.x, lo.y); cv.u[1] = pk_bf16(lo.z, lo.w);
    cv.u[2] = pk_bf16(hi.x, hi.y); cv.u[3] = pk_bf16(hi.z, hi.w);
    afr[ks] = cv.s;
  }
  #pragma unroll
  for (int nt = 0; nt < 8; ++nt) {
    f32x4 a; a[0] = a[1] = a[2] = a[3] = bias2[nt];
    acc[nt] = a;
    const unsigned short* wrow = W2b + (size_t)(nt * 16 + col) * H + kg * 8;
    #pragma unroll
    for (int ks = 0; ks < 4; ++ks) {
      union { int4 i; short8 s; } bv;
      bv.i = *(const int4*)(wrow + ks * 32);
      acc[nt] = __builtin_amdgcn_mfma_f32_16x16x32_bf16(afr[ks], bv.s, acc[nt], 0, 0, 0);
    }
  }
  #pragma unroll
  for (int nt = 0; nt < 8; ++nt) {
    int n = nt * 16 + col;
    #pragma unroll
    for (int r = 0; r < 4; ++r) {
      int m = row0 + m0 + kg * 4 + r;
      if (m < N) out[(size_t)m * H + n] = acc[nt][r];
    }
  }
}

extern "C" void kernel_launch(void* const* d_in, const int* in_sizes, int n_in,
                              void* d_out, int out_size, void* d_ws, size_t ws_size,
                              hipStream_t stream) {
  const int* src = (const int*)d_in[0];
  const int* dst = (const int*)d_in[1];
  const int* rel = (const int*)d_in[2];
  const int* inv = (const int*)d_in[3];
  const float* ent   = (const float*)d_in[4];
  const float* rhead = (const float*)d_in[5];
  const float* rtail = (const float*)d_in[6];
  const float* resent = (const float*)d_in[7];
  const float* W1 = (const float*)d_in[8];
  const float* b1 = (const float*)d_in[9];
  const float* W2 = (const float*)d_in[10];
  const float* b2 = (const float*)d_in[11];
  int E = in_sizes[0];
  int N = in_sizes[4] / H;
  int NRES_ = in_sizes[7] / H;
  float* out = (float*)d_out;

  char* ws = (char*)d_ws;
  size_t padN = (((size_t)N * 4) + 255) & ~(size_t)255;
  int* in_deg   = (int*)ws;
  int* out_flag = (int*)(ws + padN);
  int* zcount   = (int*)(ws + 2 * padN);
  size_t base = 2 * padN + 256;
  int* offs = (int*)(ws + base);  base += (((size_t)(N + 1) * 4) + 255) & ~(size_t)255;
  int* zlist = (int*)(ws + base); base += padN;
  int* bucket = (int*)(ws + base); base += (((size_t)E * 4) + 255) & ~(size_t)255;
  int* pos = (int*)(ws + base);   base += (((size_t)E * 4) + 255) & ~(size_t)255;
  float* z2t = (float*)(ws + base); base += (((size_t)H * ZLD * 4) + 255) & ~(size_t)255;
  unsigned short* W1b = (unsigned short*)(ws + base); base += (size_t)H * H * 2;
  unsigned short* W2b = (unsigned short*)(ws + base); base += (size_t)H * H * 2;
  float2* partials = (float2*)(ws + base);
  float* feat = out;  // reuse d_out as feat storage (per-row ownership in MLP)

  // zero in_deg/out_flag/zcount (contiguous)
  hipMemsetAsync(in_deg, 0, 2 * padN + 256, stream);

  int EB = (E + 255) / 256;
  int nrb = (NRES_ + 3) / 4;
  int nbz = (N + 1023) / 1024;
  int znb = (N + 2047) / 2048;
  int GB = (N + 3) / 4;
  deg_fill_kernel<<<EB + 32 + nrb, 256, 0, stream>>>(src, dst, in_deg, out_flag, pos, E,
                                                     W1, W2, W1b, W2b, resent, z2t, NRES_);
  prep_kernel<<<1 + nbz + znb, 1024, 0, stream>>>(in_deg, out_flag, offs, zlist, zcount, N,
                                                  ent, feat);
  scatter_kernel<<<EB, 256, 0, stream>>>(dst, rel, inv, offs, pos, bucket, E);
  gsim_kernel<<<ZSB + GB, 256, 0, stream>>>(offs, bucket, out_flag, rhead, rtail,
                                            feat, N, zlist, zcount, z2t, partials, NRES_);
  zmerge_kernel<<<128, 256, 0, stream>>>(zlist, zcount, partials, resent, out, NRES_);
  mlp_kernel<<<(N + 63) / 64, 256, 0, stream>>>(feat, W1b, b1, W2b, b2, out, N);
}

// Round 13
// 186.478 us; speedup vs baseline: 1.3795x; 1.3795x over previous
//
#include <hip/hip_runtime.h>
#include <math.h>

#define H 128
#define TOPK 5
#define INV_TEMP 5.0f
#define ZLD 2064      // z2t row stride in floats (non-pow2, 16B-aligned)
#define ZN 8          // zero-nodes per group
#define JQ 512        // j-columns per task (quarter of NRES)
#define ZBLK 128      // extra blocks appended to gather grid for z1 normalize

typedef __attribute__((ext_vector_type(8))) short short8;
typedef __attribute__((ext_vector_type(4))) float f32x4;

__device__ __forceinline__ unsigned bf16_rne(float x) {
  unsigned u = __float_as_uint(x);
  return (u + 0x7FFFu + ((u >> 16) & 1u)) >> 16;
}
__device__ __forceinline__ unsigned pk_bf16(float lo, float hi) {
  return bf16_rne(lo) | (bf16_rne(hi) << 16);
}

// ---------------- degree count + rank (atomic) ∥ W->MFMA-fragment repack ∥ z2t norm ----------------
// Edge blocks are atomic-bound with idle VALUs; the W-repack and z2t blocks
// run under that shadow. W1p/W2p layout: int4[nt(8)][ks(4)][lane(64)] — the
// exact fragment lane (col=lane&15, kg=lane>>4) needs, so mlp's B-loads are
// lane-consecutive (coalesced 1KB/wave) instead of 64-line scattered.
__global__ __launch_bounds__(256) void deg_fill_kernel(
    const int* __restrict__ src, const int* __restrict__ dst,
    int* __restrict__ in_deg, int* __restrict__ out_flag,
    int* __restrict__ pos, int E,
    const float* __restrict__ W1, const float* __restrict__ W2,
    int4* __restrict__ W1p, int4* __restrict__ W2p,
    const float* __restrict__ res, float* __restrict__ z2t, int NRES_)
{
  int EB = (E + 255) >> 8;
  int b = blockIdx.x;
  if (b < EB) {
    int e = b * 256 + threadIdx.x;
    if (e < E) {
      pos[e] = atomicAdd(&in_deg[dst[e]], 1);
      out_flag[src[e]] = 1;
    }
  } else if (b < EB + 16) {
    int b2 = b - EB;               // 0..15
    const float* Wsrc = (b2 < 8) ? W1 : W2;
    int4* Wdst = (b2 < 8) ? W1p : W2p;
    int g = (b2 & 7) * 256 + threadIdx.x;   // 0..2047
    int nt = g >> 8;
    int ks = (g >> 6) & 3;
    int lane = g & 63;
    int col = lane & 15;
    int kg = lane >> 4;
    const float* srcp = Wsrc + (size_t)(nt * 16 + col) * H + ks * 32 + kg * 8;
    float4 lo = *(const float4*)(srcp);
    float4 hi = *(const float4*)(srcp + 4);
    int4 pk;
    pk.x = (int)pk_bf16(lo.x, lo.y);
    pk.y = (int)pk_bf16(lo.z, lo.w);
    pk.z = (int)pk_bf16(hi.x, hi.y);
    pk.w = (int)pk_bf16(hi.z, hi.w);
    Wdst[g] = pk;
  } else {
    int r = (b - EB - 16) * 4 + (threadIdx.x >> 6);
    int lane = threadIdx.x & 63;
    if (r < NRES_) {
      float x0 = res[(size_t)r * H + lane];
      float x1 = res[(size_t)r * H + lane + 64];
      float ss = x0 * x0 + x1 * x1;
      #pragma unroll
      for (int off = 32; off > 0; off >>= 1) ss += __shfl_xor(ss, off, 64);
      float iv = 1.0f / fmaxf(sqrtf(ss), 1e-12f);
      z2t[(size_t)lane * ZLD + r] = x0 * iv;
      z2t[(size_t)(lane + 64) * ZLD + r] = x1 * iv;
    }
  }
}

// ---------------- atomic-free bucket scatter ----------------
__global__ __launch_bounds__(256) void scatter_kernel(
    const int* __restrict__ dst, const int* __restrict__ rel, const int* __restrict__ inv,
    const int* __restrict__ offs, const int* __restrict__ pos,
    int* __restrict__ bucket, int E)
{
  int e = blockIdx.x * 256 + threadIdx.x;
  if (e < E)
    bucket[offs[dst[e]] + pos[e]] = rel[e] | (inv[e] << 16);
}

// ---------------- fused: scan (block 0) + zerolist ----------------
__global__ __launch_bounds__(1024) void prep_kernel(
    const int* __restrict__ in_deg, const int* __restrict__ out_flag,
    int* __restrict__ offs,
    int* __restrict__ zlist, int* __restrict__ zcount, int N)
{
  __shared__ int sums[1024];
  int b = blockIdx.x;
  if (b == 0) {
    int tid = threadIdx.x;
    int per = (((N + 1023) >> 10) + 3) & ~3;
    int start = tid * per;
    int end = min(start + per, N);
    int s = 0;
    int i = start;
    for (; i + 4 <= end; i += 4) {
      int4 v = *(const int4*)&in_deg[i];
      s += v.x + v.y + v.z + v.w;
    }
    for (; i < end; ++i) s += in_deg[i];
    sums[tid] = s;
    __syncthreads();
    for (int off = 1; off < 1024; off <<= 1) {
      int v = (tid >= off) ? sums[tid - off] : 0;
      __syncthreads();
      sums[tid] += v;
      __syncthreads();
    }
    int run = (tid == 0) ? 0 : sums[tid - 1];
    i = start;
    for (; i + 4 <= end; i += 4) {
      int4 v = *(const int4*)&in_deg[i];
      int4 o;
      o.x = run; run += v.x;
      o.y = run; run += v.y;
      o.z = run; run += v.z;
      o.w = run; run += v.w;
      *(int4*)&offs[i] = o;
    }
    for (; i < end; ++i) { offs[i] = run; run += in_deg[i]; }
    if (tid == 1023) offs[N] = sums[1023];
  } else {
    int n = (b - 1) * 1024 + threadIdx.x;
    if (n < N && (in_deg[n] | out_flag[n]) == 0) {
      int p = atomicAdd(zcount, 1);
      zlist[p] = n;
    }
  }
}

// ---------------- per-node mean gather + (appended blocks) z1 normalize ----------------
__global__ __launch_bounds__(256) void gather_kernel(
    const int* __restrict__ offs, const int* __restrict__ bucket,
    const int* __restrict__ out_flag,
    const float* __restrict__ rhead, const float* __restrict__ rtail,
    float* __restrict__ feat, int N, int GB,
    const int* __restrict__ zlist, const int* __restrict__ zcount,
    const float* __restrict__ ent)
{
  int lane = threadIdx.x & 63;
  if ((int)blockIdx.x >= GB) {
    int Z = *zcount;
    int wid0 = ((blockIdx.x - GB) << 2) + (threadIdx.x >> 6);
    int nwv = (gridDim.x - GB) << 2;
    for (int i = wid0; i < Z; i += nwv) {
      int n = zlist[i];
      float x0 = ent[(size_t)n * H + lane];
      float x1 = ent[(size_t)n * H + lane + 64];
      float ss = x0 * x0 + x1 * x1;
      #pragma unroll
      for (int off = 32; off > 0; off >>= 1) ss += __shfl_xor(ss, off, 64);
      float iv = 1.0f / fmaxf(sqrtf(ss), 1e-12f);
      feat[(size_t)n * H + lane] = x0 * iv;
      feat[(size_t)n * H + lane + 64] = x1 * iv;
    }
    return;
  }
  int wid = (blockIdx.x * 256 + threadIdx.x) >> 6;
  if (wid >= N) return;
  int b = offs[wid], e2 = offs[wid + 1];
  int deg = e2 - b;
  if (deg == 0 && out_flag[wid] == 0) return;   // z1 row lives here
  float a0 = 0.f, a1 = 0.f;
  int pay = (b < e2) ? bucket[b] : 0;
  for (int p = b; p < e2; ++p) {
    int pn = (p + 1 < e2) ? bucket[p + 1] : 0;
    int r = pay & 0xFFFF;
    const float* row = ((pay >> 16) ? rhead : rtail) + (size_t)r * H;
    a0 += row[lane];
    a1 += row[lane + 64];
    pay = pn;
  }
  float sc = 1.0f / (float)(deg > 0 ? deg : 1);
  feat[(size_t)wid * H + lane] = a0 * sc;
  feat[(size_t)wid * H + lane + 64] = a1 * sc;
}

// ---------------- zero-node sims + partial top-5 per (group, j-quarter) ----------------
__global__ __launch_bounds__(256) void zero_sims_kernel(
    const int* __restrict__ zlist, const int* __restrict__ zcount,
    const float* __restrict__ z1g, const float* __restrict__ z2t,
    float2* __restrict__ partials, int NRES_)
{
  __shared__ __align__(16) float sims[ZN * JQ];   // 16 KB
  int t = threadIdx.x;
  int w = t >> 6;
  int lane = t & 63;
  int Z = *zcount;
  if (Z <= 0) return;
  int ntasks = ((Z + ZN - 1) / ZN) * 4;
  for (int task = blockIdx.x; task < ntasks; task += gridDim.x) {
    int g = task >> 2, q = task & 3;
    int zi0 = g * ZN;
    int nv = min(ZN, Z - zi0);
    const float* zp[ZN];
    #pragma unroll
    for (int n = 0; n < ZN; ++n) {
      int zi = zi0 + n; if (zi > Z - 1) zi = Z - 1;
      int node = __builtin_amdgcn_readfirstlane(zlist[zi]);
      zp[n] = z1g + (size_t)node * H;
    }
    int jl0 = 2 * t;
    const float* zc = z2t + q * JQ + jl0;
    float acc[ZN][2];
    #pragma unroll
    for (int n = 0; n < ZN; ++n) { acc[n][0] = 0.f; acc[n][1] = 0.f; }
    #pragma unroll 2
    for (int k0 = 0; k0 < H; k0 += 4) {
      float2 c0 = *(const float2*)(zc + (size_t)(k0 + 0) * ZLD);
      float2 c1 = *(const float2*)(zc + (size_t)(k0 + 1) * ZLD);
      float2 c2 = *(const float2*)(zc + (size_t)(k0 + 2) * ZLD);
      float2 c3 = *(const float2*)(zc + (size_t)(k0 + 3) * ZLD);
      #pragma unroll
      for (int n = 0; n < ZN; ++n) {
        float4 z = *(const float4*)(zp[n] + k0);   // SGPR base -> s_load
        acc[n][0] = fmaf(z.x, c0.x, acc[n][0]);
        acc[n][1] = fmaf(z.x, c0.y, acc[n][1]);
        acc[n][0] = fmaf(z.y, c1.x, acc[n][0]);
        acc[n][1] = fmaf(z.y, c1.y, acc[n][1]);
        acc[n][0] = fmaf(z.z, c2.x, acc[n][0]);
        acc[n][1] = fmaf(z.z, c2.y, acc[n][1]);
        acc[n][0] = fmaf(z.w, c3.x, acc[n][0]);
        acc[n][1] = fmaf(z.w, c3.y, acc[n][1]);
      }
    }
    int j0g = q * JQ + jl0;
    #pragma unroll
    for (int n = 0; n < ZN; ++n) {
      float v0 = (j0g + 0 < NRES_) ? acc[n][0] : -1e30f;
      float v1 = (j0g + 1 < NRES_) ? acc[n][1] : -1e30f;
      *(float2*)&sims[n * JQ + jl0] = make_float2(v0, v1);
    }
    __syncthreads();
    #pragma unroll
    for (int c = 0; c < 2; ++c) {
      int nl = w * 2 + c;
      if (nl < nv) {
        float tv[TOPK]; int ti[TOPK];
        #pragma unroll
        for (int k = 0; k < TOPK; ++k) { tv[k] = -1e30f; ti[k] = 0x7fffffff; }
        #pragma unroll
        for (int i = 0; i < JQ / 64; ++i) {
          int jl = i * 64 + lane;
          float s = sims[nl * JQ + jl];
          int j = q * JQ + jl;
          if (s > tv[TOPK - 1] || (s == tv[TOPK - 1] && j < ti[TOPK - 1])) {
            tv[TOPK - 1] = s; ti[TOPK - 1] = j;
            #pragma unroll
            for (int k = TOPK - 1; k > 0; --k) {
              if (tv[k] > tv[k - 1] || (tv[k] == tv[k - 1] && ti[k] < ti[k - 1])) {
                float a = tv[k]; tv[k] = tv[k - 1]; tv[k - 1] = a;
                int bI = ti[k]; ti[k] = ti[k - 1]; ti[k - 1] = bI;
              }
            }
          }
        }
        #pragma unroll
        for (int r = 0; r < TOPK; ++r) {
          float bv = tv[0]; int bi = ti[0];
          #pragma unroll
          for (int k = 1; k < TOPK; ++k)
            if (tv[k] > bv || (tv[k] == bv && ti[k] < bi)) { bv = tv[k]; bi = ti[k]; }
          #pragma unroll
          for (int off = 32; off > 0; off >>= 1) {
            float ov = __shfl_xor(bv, off, 64);
            int oi = __shfl_xor(bi, off, 64);
            if (ov > bv || (ov == bv && oi < bi)) { bv = ov; bi = oi; }
          }
          if (lane == r)
            partials[((size_t)task * ZN + nl) * TOPK + r] =
                make_float2(bv, __int_as_float(bi));
          #pragma unroll
          for (int k = 0; k < TOPK; ++k)
            if (ti[k] == bi) tv[k] = -1e30f;
        }
      }
    }
    __syncthreads();
  }
}

// ---------------- merge 4 quarter top-5s -> softmax -> weighted sum ----------------
__global__ __launch_bounds__(256) void zmerge_kernel(
    const int* __restrict__ zlist, const int* __restrict__ zcount,
    const float2* __restrict__ partials, const float* __restrict__ res_raw,
    float* __restrict__ feat, int NRES_)
{
  int gid = blockIdx.x * 256 + threadIdx.x;
  int wid = gid >> 6;
  int lane = gid & 63;
  int nw = (gridDim.x * 256) >> 6;
  int Z = *zcount;
  for (int nz = wid; nz < Z; nz += nw) {
    int g = nz >> 3, w = nz & 7;
    float v = -1e30f; int idx = 0x7fffffff;
    if (lane < 4 * TOPK) {
      int q = lane / TOPK, k = lane - q * TOPK;
      float2 p = partials[((size_t)(g * 4 + q) * ZN + w) * TOPK + k];
      v = p.x; idx = __float_as_int(p.y);
    }
    bool used = false;
    float m = 0.f, wsum = 0.f, a0 = 0.f, a1 = 0.f;
    #pragma unroll
    for (int r = 0; r < TOPK; ++r) {
      float bv = used ? -1e31f : v;
      int bi = used ? 0x7fffffff : idx;
      #pragma unroll
      for (int off = 32; off > 0; off >>= 1) {
        float ov = __shfl_xor(bv, off, 64);
        int oi = __shfl_xor(bi, off, 64);
        if (ov > bv || (ov == bv && oi < bi)) { bv = ov; bi = oi; }
      }
      if (r == 0) m = bv;
      bool ok = (unsigned)bi < (unsigned)NRES_;
      float wk = ok ? expf((bv - m) * INV_TEMP) : 0.f;
      wsum += wk;
      const float* rr = res_raw + (size_t)(ok ? bi : 0) * H;
      a0 += wk * rr[lane];
      a1 += wk * rr[lane + 64];
      if (idx == bi) used = true;
    }
    float inv_ws = 1.0f / wsum;
    int n = zlist[nz];
    feat[(size_t)n * H + lane] = a0 * inv_ws;
    feat[(size_t)n * H + lane + 64] = a1 * inv_ws;
  }
}

// ---------------- fused 2-layer MLP via bf16 MFMA (pre-packed W fragments) ----------------
__global__ __launch_bounds__(256) void mlp_kernel(
    const float* __restrict__ feat,
    const int4* __restrict__ W1p, const float* __restrict__ b1,
    const int4* __restrict__ W2p, const float* __restrict__ b2,
    float* __restrict__ out, int N)
{
  __shared__ float lds[64 * 128];   // 32 KB
  char* ldsb = (char*)lds;
  int t = threadIdx.x;
  int lane = t & 63;
  int w = t >> 6;
  int row0 = blockIdx.x * 64;

  for (int idx = t; idx < 64 * 32; idx += 256) {
    int r = idx >> 5, q = idx & 31;
    float4 v = make_float4(0.f, 0.f, 0.f, 0.f);
    if (row0 + r < N) v = *(const float4*)&feat[(size_t)(row0 + r) * H + q * 4];
    int byte = (r * 512 + q * 16) ^ ((r & 7) << 4);
    *(float4*)(ldsb + byte) = v;
  }
  __syncthreads();

  int m0 = w * 16;
  int col = lane & 15;
  int kg = lane >> 4;
  int am = m0 + col;
  int aswz = (am & 7) << 4;

  float bias1[8], bias2[8];
  #pragma unroll
  for (int nt = 0; nt < 8; ++nt) {
    bias1[nt] = b1[nt * 16 + col];
    bias2[nt] = b2[nt * 16 + col];
  }

  short8 afr[4];
  f32x4 acc[8];

  // ---- layer 1 ----
  #pragma unroll
  for (int ks = 0; ks < 4; ++ks) {
    int base = am * 512 + ks * 128 + kg * 32;
    float4 lo = *(float4*)(ldsb + (base ^ aswz));
    float4 hi = *(float4*)(ldsb + ((base + 16) ^ aswz));
    union { unsigned u[4]; short8 s; } cv;
    cv.u[0] = pk_bf16(lo.x, lo.y); cv.u[1] = pk_bf16(lo.z, lo.w);
    cv.u[2] = pk_bf16(hi.x, hi.y); cv.u[3] = pk_bf16(hi.z, hi.w);
    afr[ks] = cv.s;
  }
  #pragma unroll
  for (int nt = 0; nt < 8; ++nt) {
    f32x4 a; a[0] = a[1] = a[2] = a[3] = bias1[nt];
    acc[nt] = a;
    #pragma unroll
    for (int ks = 0; ks < 4; ++ks) {
      union { int4 i; short8 s; } bv;
      bv.i = W1p[(nt * 4 + ks) * 64 + lane];   // coalesced: lane-consecutive
      acc[nt] = __builtin_amdgcn_mfma_f32_16x16x32_bf16(afr[ks], bv.s, acc[nt], 0, 0, 0);
    }
  }
  __syncthreads();
  #pragma unroll
  for (int nt = 0; nt < 8; ++nt) {
    int n = nt * 16 + col;
    #pragma unroll
    for (int r = 0; r < 4; ++r) {
      int m = m0 + kg * 4 + r;
      int byte = (m * 512 + n * 4) ^ ((m & 7) << 4);
      *(float*)(ldsb + byte) = fmaxf(acc[nt][r], 0.f);
    }
  }
  __syncthreads();

  // ---- layer 2 ----
  #pragma unroll
  for (int ks = 0; ks < 4; ++ks) {
    int base = am * 512 + ks * 128 + kg * 32;
    float4 lo = *(float4*)(ldsb + (base ^ aswz));
    float4 hi = *(float4*)(ldsb + ((base + 16) ^ aswz));
    union { unsigned u[4]; short8 s; } cv;
    cv.u[0] = pk_bf16(lo.x, lo.y); cv.u[1] = pk_bf16(lo.z, lo.w);
    cv.u[2] = pk_bf16(hi.x, hi.y); cv.u[3] = pk_bf16(hi.z, hi.w);
    afr[ks] = cv.s;
  }
  #pragma unroll
  for (int nt = 0; nt < 8; ++nt) {
    f32x4 a; a[0] = a[1] = a[2] = a[3] = bias2[nt];
    acc[nt] = a;
    #pragma unroll
    for (int ks = 0; ks < 4; ++ks) {
      union { int4 i; short8 s; } bv;
      bv.i = W2p[(nt * 4 + ks) * 64 + lane];   // coalesced
      acc[nt] = __builtin_amdgcn_mfma_f32_16x16x32_bf16(afr[ks], bv.s, acc[nt], 0, 0, 0);
    }
  }
  #pragma unroll
  for (int nt = 0; nt < 8; ++nt) {
    int n = nt * 16 + col;
    #pragma unroll
    for (int r = 0; r < 4; ++r) {
      int m = row0 + m0 + kg * 4 + r;
      if (m < N) out[(size_t)m * H + n] = acc[nt][r];
    }
  }
}

extern "C" void kernel_launch(void* const* d_in, const int* in_sizes, int n_in,
                              void* d_out, int out_size, void* d_ws, size_t ws_size,
                              hipStream_t stream) {
  const int* src = (const int*)d_in[0];
  const int* dst = (const int*)d_in[1];
  const int* rel = (const int*)d_in[2];
  const int* inv = (const int*)d_in[3];
  const float* ent   = (const float*)d_in[4];
  const float* rhead = (const float*)d_in[5];
  const float* rtail = (const float*)d_in[6];
  const float* resent = (const float*)d_in[7];
  const float* W1 = (const float*)d_in[8];
  const float* b1 = (const float*)d_in[9];
  const float* W2 = (const float*)d_in[10];
  const float* b2 = (const float*)d_in[11];
  int E = in_sizes[0];
  int N = in_sizes[4] / H;
  int NRES_ = in_sizes[7] / H;
  float* out = (float*)d_out;

  char* ws = (char*)d_ws;
  size_t padN = (((size_t)N * 4) + 255) & ~(size_t)255;
  int* in_deg   = (int*)ws;
  int* out_flag = (int*)(ws + padN);
  int* zcount   = (int*)(ws + 2 * padN);
  size_t base = 2 * padN + 256;
  int* offs = (int*)(ws + base);  base += (((size_t)(N + 1) * 4) + 255) & ~(size_t)255;
  int* zlist = (int*)(ws + base); base += padN;
  int* bucket = (int*)(ws + base); base += (((size_t)E * 4) + 255) & ~(size_t)255;
  int* pos = (int*)(ws + base);   base += (((size_t)E * 4) + 255) & ~(size_t)255;
  float* z2t = (float*)(ws + base); base += (((size_t)H * ZLD * 4) + 255) & ~(size_t)255;
  int4* W1p = (int4*)(ws + base); base += 2048 * sizeof(int4);
  int4* W2p = (int4*)(ws + base); base += 2048 * sizeof(int4);
  float2* partials = (float2*)(ws + base);
  float* feat = out;  // reuse d_out as feat storage (per-row ownership in MLP)

  // zero in_deg/out_flag/zcount (contiguous)
  hipMemsetAsync(in_deg, 0, 2 * padN + 256, stream);

  int EB = (E + 255) / 256;
  int nrb = (NRES_ + 3) / 4;
  int nbz = (N + 1023) / 1024;
  int GB = (N + 3) / 4;
  deg_fill_kernel<<<EB + 16 + nrb, 256, 0, stream>>>(src, dst, in_deg, out_flag, pos, E,
                                                     W1, W2, W1p, W2p, resent, z2t, NRES_);
  prep_kernel<<<1 + nbz, 1024, 0, stream>>>(in_deg, out_flag, offs, zlist, zcount, N);
  scatter_kernel<<<EB, 256, 0, stream>>>(dst, rel, inv, offs, pos, bucket, E);
  gather_kernel<<<GB + ZBLK, 256, 0, stream>>>(offs, bucket, out_flag, rhead, rtail,
                                               feat, N, GB, zlist, zcount, ent);
  zero_sims_kernel<<<1024, 256, 0, stream>>>(zlist, zcount, feat, z2t, partials, NRES_);
  zmerge_kernel<<<128, 256, 0, stream>>>(zlist, zcount, partials, resent, out, NRES_);
  mlp_kernel<<<(N + 63) / 64, 256, 0, stream>>>(feat, W1p, b1, W2p, b2, out, N);
}